// Round 5
// baseline (377.558 us; speedup 1.0000x reference)
//
#include <hip/hip_runtime.h>
#include <math.h>

#define S_ 2048
#define E_ 2048
#define H_ 16
#define D_ 128

typedef _Float16 f16;
typedef _Float16 f16x8 __attribute__((ext_vector_type(8)));
typedef _Float16 f16x4 __attribute__((ext_vector_type(4)));
typedef float f32x4 __attribute__((ext_vector_type(4)));

// async global->LDS, 16B per lane. LDS dest must be wave-uniform base + lane*16.
// Used ONLY in the m97-pattern GEMMs (issue -> barrier -> consume, adjacent).
#define GLDS(g, l)                                                            \
    __builtin_amdgcn_global_load_lds(                                         \
        (const __attribute__((address_space(1))) void*)(g),                   \
        (__attribute__((address_space(3))) void*)(l), 16, 0, 0)

// ---------------------------------------------------------------- convert
// First instance also zeroes the attn work-queue counter (ws is poisoned 0xAA
// before every timed launch; stream order guarantees this runs before attn).
__global__ __launch_bounds__(256) void cvt_f32_f16(const float* __restrict__ in,
                                                   f16* __restrict__ out, int n,
                                                   unsigned* __restrict__ ctr) {
    if (ctr && blockIdx.x == 0 && threadIdx.x == 0) *ctr = 0;
    int i = (blockIdx.x * 256 + threadIdx.x) * 4;
    if (i + 3 < n) {
        float4 v = *(const float4*)(in + i);
        f16x4 o;
        o[0] = (f16)v.x; o[1] = (f16)v.y; o[2] = (f16)v.z; o[3] = (f16)v.w;
        *(f16x4*)(out + i) = o;
    }
}

// ---------------------------------------------------------------- QKV GEMM (m97 structure)
__global__ __launch_bounds__(256) void gemm_qkv(const f16* __restrict__ A,
                                                const f16* __restrict__ B,
                                                const float* __restrict__ bias,
                                                f16* __restrict__ Qm,
                                                f16* __restrict__ Km,
                                                f16* __restrict__ VTm) {
    __shared__ __align__(16) f16 As[128 * 32];   // unpadded: required by global_load_lds
    __shared__ __align__(16) f16 Bs[128 * 32];
    const int tid  = threadIdx.x;
    const int lane = tid & 63, wave = tid >> 6;
    const int lm = lane & 15, quad = lane >> 4;
    const int wm = wave >> 1, wn = wave & 1;
    const int tn0 = blockIdx.x * 128;
    const int tm0 = blockIdx.y * 128;

    const int srow = tid >> 2, scol = (tid & 3) * 8;
    const f16* Ag0 = A + (size_t)(tm0 + srow) * E_ + scol;
    const f16* Ag1 = Ag0 + (size_t)64 * E_;
    const f16* Bg0 = B + (size_t)(tn0 + srow) * E_ + scol;
    const f16* Bg1 = Bg0 + (size_t)64 * E_;
    f16* Al0 = &As[tid * 8];
    f16* Al1 = &As[(256 + tid) * 8];
    f16* Bl0 = &Bs[tid * 8];
    f16* Bl1 = &Bs[(256 + tid) * 8];

    const f32x4 vzero = {0.f, 0.f, 0.f, 0.f};
    f32x4 acc[4][4];
#pragma unroll
    for (int i = 0; i < 4; i++)
#pragma unroll
        for (int j = 0; j < 4; j++) acc[i][j] = vzero;

    for (int k0 = 0; k0 < E_; k0 += 32) {
        __syncthreads();
        GLDS(Ag0 + k0, Al0); GLDS(Ag1 + k0, Al1);
        GLDS(Bg0 + k0, Bl0); GLDS(Bg1 + k0, Bl1);
        __syncthreads();
        f16x8 af[4], bfr[4];
#pragma unroll
        for (int i = 0; i < 4; i++)
            af[i] = *(const f16x8*)&As[(wm * 64 + i * 16 + lm) * 32 + quad * 8];
#pragma unroll
        for (int j = 0; j < 4; j++)
            bfr[j] = *(const f16x8*)&Bs[(wn * 64 + j * 16 + lm) * 32 + quad * 8];
#pragma unroll
        for (int i = 0; i < 4; i++)
#pragma unroll
            for (int j = 0; j < 4; j++)
                acc[i][j] = __builtin_amdgcn_mfma_f32_16x16x32_f16(af[i], bfr[j],
                                                                   acc[i][j], 0, 0, 0);
    }

    const float qscale = 0.08838834764831845f;  // 1/sqrt(128), prefolded into Q
#pragma unroll
    for (int i = 0; i < 4; i++) {
#pragma unroll
        for (int j = 0; j < 4; j++) {
            const int n = tn0 + wn * 64 + j * 16 + lm;
            const int which = n >> 11;
            const int h = (n >> 7) & 15;
            const int d = n & 127;
            const float bv = bias[n];
#pragma unroll
            for (int r = 0; r < 4; r++) {
                const int m = tm0 + wm * 64 + i * 16 + quad * 4 + r;
                float fv = acc[i][j][r] + bv;
                if (which == 0)      Qm[((size_t)h * S_ + m) * D_ + d] = (f16)(fv * qscale);
                else if (which == 1) Km[((size_t)h * S_ + m) * D_ + d] = (f16)fv;
                else                 VTm[((size_t)h * D_ + d) * S_ + m] = (f16)fv;
            }
        }
    }
}

// ---------------------------------------------------------------- attention
// Persistent blocks + dynamic work queue (placement-independent balance).
// Items: 512 q-tiles, heavy-first (qt = 31 - idx/16, h = idx%16). Each item is
// fully owned by one block -> output bitwise deterministic regardless of which
// block grabs it. Prefetch of tile t+1 issued AFTER the second barrier so the
// compiler's vmcnt(0)-before-s_barrier drain lands ~a full compute phase after
// issue (the R4 structure drained it immediately -> exposed ~900 cyc/iter).
__global__ __launch_bounds__(256, 2) void attn(const f16* __restrict__ Qm,
                                               const f16* __restrict__ Km,
                                               const f16* __restrict__ VTm,
                                               f16* __restrict__ Om,
                                               unsigned* __restrict__ ctr) {
    __shared__ __align__(16) f16 Ks[64 * 128];    // [key][d-chunk swizzled]
    __shared__ __align__(16) f16 VTs[128 * 64];   // [d][key-chunk swizzled]
    __shared__ __align__(16) f16 Ps[4][16 * 72];  // per-wave P [qrow][key], pad 72
    __shared__ unsigned sh_item;

    const int tid  = threadIdx.x;
    const int lane = tid & 63, wave = tid >> 6;
    const int lm = lane & 15, quad = lane >> 4;

    // staging assignment: 4 Ks chunks + 4 VTs chunks of 16B per thread.
    // global offsets linear (coalesced); LDS offsets XOR-swizzled.
    int kg[4], kl[4], vg[4], vl[4];
#pragma unroll
    for (int rr = 0; rr < 4; rr++) {
        int c = rr * 256 + tid;
        int key = c >> 4, dc = c & 15;
        kg[rr] = key * 128 + dc * 8;
        kl[rr] = key * 128 + ((dc & 8) | ((dc & 7) ^ (key & 7))) * 8;
        int d = c >> 3, sc = c & 7;
        vg[rr] = d * 2048 + sc * 8;
        vl[rr] = d * 64 + (sc ^ (d & 7)) * 8;
    }

    const f32x4 vzero = {0.f, 0.f, 0.f, 0.f};

    for (;;) {
        if (tid == 0) sh_item = atomicAdd(ctr, 1u);
        __syncthreads();
        const unsigned item = sh_item;
        if (item >= 512u) break;
        const int qt = 31 - (int)(item >> 4);
        const int h  = (int)(item & 15u);
        const int nIter = qt + 1;

        const f16* KmH  = Km  + (size_t)h * S_ * D_;
        const f16* VTmH = VTm + (size_t)h * D_ * S_;
        const f16* QmH  = Qm  + (size_t)h * S_ * D_;

        f32x4 o[8];
#pragma unroll
        for (int f = 0; f < 8; f++) o[f] = vzero;
        float mi = -INFINITY, li = 0.f;

        const int q0c = qt * 64 + wave * 16;       // this wave's 16-row chunk
        f16x8 qf[4];
#pragma unroll
        for (int kc = 0; kc < 4; kc++)
            qf[kc] = *(const f16x8*)(QmH + (size_t)(q0c + lm) * D_ + kc * 32 + quad * 8);

        // prefetch tile 0 into registers
        float4 kreg[4], vreg[4];
#pragma unroll
        for (int rr = 0; rr < 4; rr++) {
            kreg[rr] = *(const float4*)(KmH + kg[rr]);
            vreg[rr] = *(const float4*)(VTmH + vg[rr]);
        }

        for (int t = 0; t < nIter; t++) {
            const int k0 = t * 64;

            __syncthreads();   // prev LDS reads done; drains prefetch issued ~1 compute phase ago
#pragma unroll
            for (int rr = 0; rr < 4; rr++) {
                *(float4*)&Ks[kl[rr]] = kreg[rr];
                *(float4*)&VTs[vl[rr]] = vreg[rr];
            }
            __syncthreads();   // lgkm drain only (vmcnt already 0)

            if (t + 1 < nIter) {   // issue next-tile prefetch at top of compute phase
                const int nt = t + 1;
#pragma unroll
                for (int rr = 0; rr < 4; rr++) {
                    kreg[rr] = *(const float4*)(KmH + (size_t)nt * 8192 + kg[rr]);
                    vreg[rr] = *(const float4*)(VTmH + nt * 64 + vg[rr]);
                }
            }

            // ---- S^T = K * Q^T : C[m=key][n=qrow]
            f32x4 sfr[4];
#pragma unroll
            for (int j = 0; j < 4; j++) {
                f32x4 a = vzero;
#pragma unroll
                for (int kc = 0; kc < 4; kc++) {
                    int dc = kc * 4 + quad;
                    int sc = (dc & 8) | ((dc & 7) ^ (lm & 7));
                    f16x8 kf = *(const f16x8*)&Ks[(j * 16 + lm) * 128 + sc * 8];
                    a = __builtin_amdgcn_mfma_f32_16x16x32_f16(kf, qf[kc], a, 0, 0, 0);
                }
                sfr[j] = a;
            }

            // ---- online softmax (qrow = q0c+lm; 16 key-scores per lane)
            const bool masked = (t == qt);
            const int qrow = q0c + lm;
            float sv[4][4];
            float vmax = -3e38f;
#pragma unroll
            for (int j = 0; j < 4; j++)
#pragma unroll
                for (int r = 0; r < 4; r++) {
                    float x = sfr[j][r];
                    if (masked) {
                        int key = k0 + j * 16 + quad * 4 + r;
                        if (key > qrow) x = -1e30f;
                    }
                    sv[j][r] = x;
                    vmax = fmaxf(vmax, x);
                }
            vmax = fmaxf(vmax, __shfl_xor(vmax, 16));
            vmax = fmaxf(vmax, __shfl_xor(vmax, 32));
            const float mn = fmaxf(mi, vmax);
            const float alpha = __expf(mi - mn);
            mi = mn;
            float rsum = 0.f;
#pragma unroll
            for (int j = 0; j < 4; j++) {
                f16x4 pk;
#pragma unroll
                for (int r = 0; r < 4; r++) {
                    float pv = __expf(sv[j][r] - mn);
                    rsum += pv;
                    pk[r] = (f16)pv;
                }
                *(f16x4*)&Ps[wave][lm * 72 + j * 16 + quad * 4] = pk;
            }
            rsum += __shfl_xor(rsum, 16);
            rsum += __shfl_xor(rsum, 32);
            li = li * alpha + rsum;
#pragma unroll
            for (int f = 0; f < 8; f++) {
                o[f][0] *= alpha; o[f][1] *= alpha; o[f][2] *= alpha; o[f][3] *= alpha;
            }

            // ---- O^T += V^T * P^T  (P read back same-wave: in-order LDS, no barrier)
            f16x8 pb[2];
#pragma unroll
            for (int kc = 0; kc < 2; kc++)
                pb[kc] = *(const f16x8*)&Ps[wave][lm * 72 + kc * 32 + quad * 8];
#pragma unroll
            for (int f = 0; f < 8; f++) {
#pragma unroll
                for (int kc = 0; kc < 2; kc++) {
                    int sc = (kc * 4 + quad) ^ (lm & 7);
                    f16x8 vf = *(const f16x8*)&VTs[(f * 16 + lm) * 64 + sc * 8];
                    o[f] = __builtin_amdgcn_mfma_f32_16x16x32_f16(vf, pb[kc], o[f], 0, 0, 0);
                }
            }
        }

        const float inv = 1.f / li;
#pragma unroll
        for (int f = 0; f < 8; f++) {
            f16x4 ov;
#pragma unroll
            for (int r = 0; r < 4; r++) ov[r] = (f16)(o[f][r] * inv);
            *(f16x4*)(Om + (size_t)(q0c + lm) * E_ + h * 128 + f * 16 + quad * 4) = ov;
        }
    }
}

// ---------------------------------------------------------------- out GEMM (m97 structure)
__global__ __launch_bounds__(256) void gemm_out(const f16* __restrict__ A,
                                                const f16* __restrict__ B,
                                                const float* __restrict__ bias,
                                                float* __restrict__ Cout) {
    __shared__ __align__(16) f16 As[128 * 32];
    __shared__ __align__(16) f16 Bs[128 * 32];
    const int tid  = threadIdx.x;
    const int lane = tid & 63, wave = tid >> 6;
    const int lm = lane & 15, quad = lane >> 4;
    const int wm = wave >> 1, wn = wave & 1;
    const int tn0 = blockIdx.x * 128;
    const int tm0 = blockIdx.y * 128;

    const int srow = tid >> 2, scol = (tid & 3) * 8;
    const f16* Ag0 = A + (size_t)(tm0 + srow) * E_ + scol;
    const f16* Ag1 = Ag0 + (size_t)64 * E_;
    const f16* Bg0 = B + (size_t)(tn0 + srow) * E_ + scol;
    const f16* Bg1 = Bg0 + (size_t)64 * E_;
    f16* Al0 = &As[tid * 8];
    f16* Al1 = &As[(256 + tid) * 8];
    f16* Bl0 = &Bs[tid * 8];
    f16* Bl1 = &Bs[(256 + tid) * 8];

    const f32x4 vzero = {0.f, 0.f, 0.f, 0.f};
    f32x4 acc[4][4];
#pragma unroll
    for (int i = 0; i < 4; i++)
#pragma unroll
        for (int j = 0; j < 4; j++) acc[i][j] = vzero;

    for (int k0 = 0; k0 < E_; k0 += 32) {
        __syncthreads();
        GLDS(Ag0 + k0, Al0); GLDS(Ag1 + k0, Al1);
        GLDS(Bg0 + k0, Bl0); GLDS(Bg1 + k0, Bl1);
        __syncthreads();
        f16x8 af[4], bfr[4];
#pragma unroll
        for (int i = 0; i < 4; i++)
            af[i] = *(const f16x8*)&As[(wm * 64 + i * 16 + lm) * 32 + quad * 8];
#pragma unroll
        for (int j = 0; j < 4; j++)
            bfr[j] = *(const f16x8*)&Bs[(wn * 64 + j * 16 + lm) * 32 + quad * 8];
#pragma unroll
        for (int i = 0; i < 4; i++)
#pragma unroll
            for (int j = 0; j < 4; j++)
                acc[i][j] = __builtin_amdgcn_mfma_f32_16x16x32_f16(af[i], bfr[j],
                                                                   acc[i][j], 0, 0, 0);
    }

#pragma unroll
    for (int i = 0; i < 4; i++) {
#pragma unroll
        for (int j = 0; j < 4; j++) {
            const int n = tn0 + wn * 64 + j * 16 + lm;
            const float bv = bias[n];
#pragma unroll
            for (int r = 0; r < 4; r++) {
                const int m = tm0 + wm * 64 + i * 16 + quad * 4 + r;
                Cout[(size_t)m * E_ + n] = acc[i][j][r] + bv;
            }
        }
    }
}

// ---------------------------------------------------------------- launch
extern "C" void kernel_launch(void* const* d_in, const int* in_sizes, int n_in,
                              void* d_out, int out_size, void* d_ws, size_t ws_size,
                              hipStream_t stream) {
    const float* x     = (const float*)d_in[0];
    const float* w_qkv = (const float*)d_in[1];
    const float* b_qkv = (const float*)d_in[2];
    const float* w_out = (const float*)d_in[3];
    const float* b_out = (const float*)d_in[4];
    float* out = (float*)d_out;

    char* ws = (char*)d_ws;
    f16* xb  = (f16*)ws; ws += (size_t)S_ * E_ * 2;
    f16* wqb = (f16*)ws; ws += (size_t)3 * E_ * E_ * 2;
    f16* wob = (f16*)ws; ws += (size_t)E_ * E_ * 2;
    f16* Qm  = (f16*)ws; ws += (size_t)H_ * S_ * D_ * 2;
    f16* Km  = (f16*)ws; ws += (size_t)H_ * S_ * D_ * 2;
    f16* VTm = (f16*)ws; ws += (size_t)H_ * D_ * S_ * 2;
    f16* Om  = (f16*)ws; ws += (size_t)S_ * E_ * 2;
    unsigned* ctr = (unsigned*)ws; ws += 256;

    cvt_f32_f16<<<4096, 256, 0, stream>>>(x, xb, S_ * E_, ctr);
    cvt_f32_f16<<<12288, 256, 0, stream>>>(w_qkv, wqb, 3 * E_ * E_, nullptr);
    cvt_f32_f16<<<4096, 256, 0, stream>>>(w_out, wob, E_ * E_, nullptr);
    gemm_qkv<<<dim3(48, 16), 256, 0, stream>>>(xb, wqb, b_qkv, Qm, Km, VTm);
    attn<<<384, 256, 0, stream>>>(Qm, Km, VTm, Om, ctr);
    gemm_out<<<dim3(16, 16), 256, 0, stream>>>(Om, wob, b_out, out);
}

// Round 6
// 330.582 us; speedup vs baseline: 1.1421x; 1.1421x over previous
//
#include <hip/hip_runtime.h>
#include <math.h>

#define S_ 2048
#define E_ 2048
#define H_ 16
#define D_ 128

typedef _Float16 f16;
typedef _Float16 f16x8 __attribute__((ext_vector_type(8)));
typedef _Float16 f16x4 __attribute__((ext_vector_type(4)));
typedef float f32x4 __attribute__((ext_vector_type(4)));

// async global->LDS, 16B per lane. LDS dest must be wave-uniform base + lane*16.
// Used ONLY in the m97-pattern GEMMs (issue -> barrier -> consume, adjacent).
#define GLDS(g, l)                                                            \
    __builtin_amdgcn_global_load_lds(                                         \
        (const __attribute__((address_space(1))) void*)(g),                   \
        (__attribute__((address_space(3))) void*)(l), 16, 0, 0)

// ---------------------------------------------------------------- convert
__global__ __launch_bounds__(256) void cvt_f32_f16(const float* __restrict__ in,
                                                   f16* __restrict__ out, int n) {
    int i = (blockIdx.x * 256 + threadIdx.x) * 4;
    if (i + 3 < n) {
        float4 v = *(const float4*)(in + i);
        f16x4 o;
        o[0] = (f16)v.x; o[1] = (f16)v.y; o[2] = (f16)v.z; o[3] = (f16)v.w;
        *(f16x4*)(out + i) = o;
    }
}

// ---------------------------------------------------------------- QKV GEMM (m97 structure)
__global__ __launch_bounds__(256) void gemm_qkv(const f16* __restrict__ A,
                                                const f16* __restrict__ B,
                                                const float* __restrict__ bias,
                                                f16* __restrict__ Qm,
                                                f16* __restrict__ Km,
                                                f16* __restrict__ VTm) {
    __shared__ __align__(16) f16 As[128 * 32];   // unpadded: required by global_load_lds
    __shared__ __align__(16) f16 Bs[128 * 32];
    const int tid  = threadIdx.x;
    const int lane = tid & 63, wave = tid >> 6;
    const int lm = lane & 15, quad = lane >> 4;
    const int wm = wave >> 1, wn = wave & 1;
    const int tn0 = blockIdx.x * 128;
    const int tm0 = blockIdx.y * 128;

    const int srow = tid >> 2, scol = (tid & 3) * 8;
    const f16* Ag0 = A + (size_t)(tm0 + srow) * E_ + scol;
    const f16* Ag1 = Ag0 + (size_t)64 * E_;
    const f16* Bg0 = B + (size_t)(tn0 + srow) * E_ + scol;
    const f16* Bg1 = Bg0 + (size_t)64 * E_;
    f16* Al0 = &As[tid * 8];
    f16* Al1 = &As[(256 + tid) * 8];
    f16* Bl0 = &Bs[tid * 8];
    f16* Bl1 = &Bs[(256 + tid) * 8];

    const f32x4 vzero = {0.f, 0.f, 0.f, 0.f};
    f32x4 acc[4][4];
#pragma unroll
    for (int i = 0; i < 4; i++)
#pragma unroll
        for (int j = 0; j < 4; j++) acc[i][j] = vzero;

    for (int k0 = 0; k0 < E_; k0 += 32) {
        __syncthreads();
        GLDS(Ag0 + k0, Al0); GLDS(Ag1 + k0, Al1);
        GLDS(Bg0 + k0, Bl0); GLDS(Bg1 + k0, Bl1);
        __syncthreads();
        f16x8 af[4], bfr[4];
#pragma unroll
        for (int i = 0; i < 4; i++)
            af[i] = *(const f16x8*)&As[(wm * 64 + i * 16 + lm) * 32 + quad * 8];
#pragma unroll
        for (int j = 0; j < 4; j++)
            bfr[j] = *(const f16x8*)&Bs[(wn * 64 + j * 16 + lm) * 32 + quad * 8];
#pragma unroll
        for (int i = 0; i < 4; i++)
#pragma unroll
            for (int j = 0; j < 4; j++)
                acc[i][j] = __builtin_amdgcn_mfma_f32_16x16x32_f16(af[i], bfr[j],
                                                                   acc[i][j], 0, 0, 0);
    }

    // Q prescale: 1/sqrt(128) * log2(e)  (softmax uses exp2 directly)
    const float qscale = 0.12751780056045268f;
#pragma unroll
    for (int i = 0; i < 4; i++) {
#pragma unroll
        for (int j = 0; j < 4; j++) {
            const int n = tn0 + wn * 64 + j * 16 + lm;
            const int which = n >> 11;
            const int h = (n >> 7) & 15;
            const int d = n & 127;
            const float bv = bias[n];
#pragma unroll
            for (int r = 0; r < 4; r++) {
                const int m = tm0 + wm * 64 + i * 16 + quad * 4 + r;
                float fv = acc[i][j][r] + bv;
                if (which == 0)      Qm[((size_t)h * S_ + m) * D_ + d] = (f16)(fv * qscale);
                else if (which == 1) Km[((size_t)h * S_ + m) * D_ + d] = (f16)fv;
                else                 VTm[((size_t)h * D_ + d) * S_ + m] = (f16)fv;
            }
        }
    }
}

// ---------------------------------------------------------------- attention
// Flash-decoding split, static grid 768 = 3 bands x 256:
//   band0/1: halves of heavy q-tiles (qt=16..31), partial (O,m,l) -> ws
//   band2:   light q-tiles (qt=0..15), direct Om write
// CU c (round-robin) hosts units of ~equal length summing to ~33 kv-iters ->
// co-resident blocks overlap their latency chains for their FULL duration
// (R4's heavy+light pairing left heavy blocks running solo ~72% of the time).
// Prefetch for tile t+1 issued after bar2 so the compiler's vmcnt(0) drain
// (before next iter's bar1) lands a full compute phase after issue.
__global__ __launch_bounds__(256, 3) void attn(const f16* __restrict__ Qm,
                                               const f16* __restrict__ Km,
                                               const f16* __restrict__ VTm,
                                               f16* __restrict__ Om,
                                               float* __restrict__ Opart,
                                               float2* __restrict__ MLpart) {
    __shared__ __align__(16) f16 Ks[64 * 128];    // [key][d-chunk swizzled]
    __shared__ __align__(16) f16 VTs[128 * 64];   // [d][key-chunk swizzled]
    __shared__ __align__(16) f16 Ps[4][16 * 72];  // per-wave P [qrow][key], pad 72

    const int tid  = threadIdx.x;
    const int lane = tid & 63, wave = tid >> 6;
    const int lm = lane & 15, quad = lane >> 4;
    const int b = blockIdx.x;
    const int band = b >> 8;           // 0,1 = split halves; 2 = light tiles
    const int c = b & 255;
    const int g = c >> 4, h = c & 15;

    int qt, t0, t1;
    bool split;
    if (band < 2) {
        qt = 31 - g;                    // heavy-first
        const int n = qt + 1, half = (n + 1) >> 1;
        split = true;
        if (band == 0) { t0 = 0; t1 = half; }
        else           { t0 = half; t1 = n; }
    } else {
        qt = g;                         // light band ascending: CU totals ~flat
        t0 = 0; t1 = qt + 1;
        split = false;
    }

    const f16* KmH  = Km  + (size_t)h * S_ * D_;
    const f16* VTmH = VTm + (size_t)h * D_ * S_;
    const f16* QmH  = Qm  + (size_t)h * S_ * D_;

    // staging: 4 Ks + 4 VTs 16B chunks per thread; global linear, LDS swizzled
    int kg[4], kl[4], vg[4], vl[4];
#pragma unroll
    for (int rr = 0; rr < 4; rr++) {
        int cc = rr * 256 + tid;
        int key = cc >> 4, dc = cc & 15;
        kg[rr] = key * 128 + dc * 8;
        kl[rr] = key * 128 + ((dc & 8) | ((dc & 7) ^ (key & 7))) * 8;
        int d = cc >> 3, sc = cc & 7;
        vg[rr] = d * 2048 + sc * 8;
        vl[rr] = d * 64 + (sc ^ (d & 7)) * 8;
    }

    const f32x4 vzero = {0.f, 0.f, 0.f, 0.f};
    f32x4 o[8];
#pragma unroll
    for (int f = 0; f < 8; f++) o[f] = vzero;
    float mi = -INFINITY, li = 0.f;

    const int q0c = qt * 64 + wave * 16;           // this wave's 16-row chunk
    f16x8 qf[4];
#pragma unroll
    for (int kc = 0; kc < 4; kc++)
        qf[kc] = *(const f16x8*)(QmH + (size_t)(q0c + lm) * D_ + kc * 32 + quad * 8);

    // prefetch tile t0 into registers
    float4 kreg[4], vreg[4];
#pragma unroll
    for (int rr = 0; rr < 4; rr++) {
        kreg[rr] = *(const float4*)(KmH + (size_t)t0 * 8192 + kg[rr]);
        vreg[rr] = *(const float4*)(VTmH + t0 * 64 + vg[rr]);
    }

    for (int t = t0; t < t1; t++) {
        const int k0 = t * 64;

        __syncthreads();   // prev LDS reads done; drains prefetch issued a phase ago
#pragma unroll
        for (int rr = 0; rr < 4; rr++) {
            *(float4*)&Ks[kl[rr]] = kreg[rr];
            *(float4*)&VTs[vl[rr]] = vreg[rr];
        }
        __syncthreads();   // lgkm drain only (vmcnt already 0)

        if (t + 1 < t1) {  // issue next-tile prefetch at top of compute phase
            const int nt = t + 1;
#pragma unroll
            for (int rr = 0; rr < 4; rr++) {
                kreg[rr] = *(const float4*)(KmH + (size_t)nt * 8192 + kg[rr]);
                vreg[rr] = *(const float4*)(VTmH + nt * 64 + vg[rr]);
            }
        }

        // ---- S^T = K * Q^T : C[m=key][n=qrow]
        f32x4 sfr[4];
#pragma unroll
        for (int j = 0; j < 4; j++) {
            f32x4 a = vzero;
#pragma unroll
            for (int kc = 0; kc < 4; kc++) {
                int dc = kc * 4 + quad;
                int sc = (dc & 8) | ((dc & 7) ^ (lm & 7));
                f16x8 kf = *(const f16x8*)&Ks[(j * 16 + lm) * 128 + sc * 8];
                a = __builtin_amdgcn_mfma_f32_16x16x32_f16(kf, qf[kc], a, 0, 0, 0);
            }
            sfr[j] = a;
        }

        // ---- online softmax, log2 domain (qrow = q0c+lm; 16 key-scores/lane)
        const bool masked = (t == qt);
        const int qrow = q0c + lm;
        float sv[4][4];
        float vmax = -3e38f;
#pragma unroll
        for (int j = 0; j < 4; j++)
#pragma unroll
            for (int r = 0; r < 4; r++) {
                float x = sfr[j][r];
                if (masked) {
                    int key = k0 + j * 16 + quad * 4 + r;
                    if (key > qrow) x = -1e30f;
                }
                sv[j][r] = x;
                vmax = fmaxf(vmax, x);
            }
        vmax = fmaxf(vmax, __shfl_xor(vmax, 16));
        vmax = fmaxf(vmax, __shfl_xor(vmax, 32));
        const float mn = fmaxf(mi, vmax);
        const float alpha = exp2f(mi - mn);
        mi = mn;
        float rsum = 0.f;
#pragma unroll
        for (int j = 0; j < 4; j++) {
            f16x4 pk;
#pragma unroll
            for (int r = 0; r < 4; r++) {
                float pv = exp2f(sv[j][r] - mn);
                rsum += pv;
                pk[r] = (f16)pv;
            }
            *(f16x4*)&Ps[wave][lm * 72 + j * 16 + quad * 4] = pk;
        }
        rsum += __shfl_xor(rsum, 16);
        rsum += __shfl_xor(rsum, 32);
        li = li * alpha + rsum;
#pragma unroll
        for (int f = 0; f < 8; f++) {
            o[f][0] *= alpha; o[f][1] *= alpha; o[f][2] *= alpha; o[f][3] *= alpha;
        }

        // ---- O^T += V^T * P^T  (P read back same-wave: in-order LDS, no barrier)
        f16x8 pb[2];
#pragma unroll
        for (int kc = 0; kc < 2; kc++)
            pb[kc] = *(const f16x8*)&Ps[wave][lm * 72 + kc * 32 + quad * 8];
#pragma unroll
        for (int f = 0; f < 8; f++) {
#pragma unroll
            for (int kc = 0; kc < 2; kc++) {
                int sc = (kc * 4 + quad) ^ (lm & 7);
                f16x8 vf = *(const f16x8*)&VTs[(f * 16 + lm) * 64 + sc * 8];
                o[f] = __builtin_amdgcn_mfma_f32_16x16x32_f16(vf, pb[kc], o[f], 0, 0, 0);
            }
        }
    }

    if (!split) {
        const float inv = 1.f / li;
#pragma unroll
        for (int f = 0; f < 8; f++) {
            f16x4 ov;
#pragma unroll
            for (int r = 0; r < 4; r++) ov[r] = (f16)(o[f][r] * inv);
            *(f16x4*)(Om + (size_t)(q0c + lm) * E_ + h * 128 + f * 16 + quad * 4) = ov;
        }
    } else {
        // unscaled partial O (f32) + (m,l) per row
        float* Ob = Opart + ((size_t)band * 256 + c) * (64 * 128);
        const int row = wave * 16 + lm;
#pragma unroll
        for (int f = 0; f < 8; f++)
            *(f32x4*)(Ob + row * 128 + f * 16 + quad * 4) = o[f];
        if (quad == 0)
            MLpart[((size_t)band * 256 + c) * 64 + row] = make_float2(mi, li);
    }
}

// ---------------------------------------------------------------- combine split partials
__global__ __launch_bounds__(256) void attn_combine(const float* __restrict__ Opart,
                                                    const float2* __restrict__ MLpart,
                                                    f16* __restrict__ Om) {
    const int c = blockIdx.x;                     // tile: qt = 31-(c>>4), h = c&15
    const int t = threadIdx.x;
    const int qt = 31 - (c >> 4), h = c & 15, q0 = qt * 64;
    const float* O1 = Opart + (size_t)c * (64 * 128);
    const float* O2 = Opart + (size_t)(256 + c) * (64 * 128);
    const float2* ml1 = MLpart + (size_t)c * 64;
    const float2* ml2 = MLpart + (size_t)(256 + c) * 64;
#pragma unroll
    for (int i = 0; i < 8; i++) {
        const int chunk = i * 256 + t;
        const int row = chunk >> 5, dc = chunk & 31;
        const float2 a = ml1[row], bm = ml2[row];
        const float M = fmaxf(a.x, bm.x);
        const float w1 = exp2f(a.x - M), w2 = exp2f(bm.x - M);
        const float inv = 1.f / (w1 * a.y + w2 * bm.y);
        const f32x4 o1 = *(const f32x4*)(O1 + row * 128 + dc * 4);
        const f32x4 o2 = *(const f32x4*)(O2 + row * 128 + dc * 4);
        f16x4 ov;
#pragma unroll
        for (int r = 0; r < 4; r++) ov[r] = (f16)((w1 * o1[r] + w2 * o2[r]) * inv);
        *(f16x4*)(Om + (size_t)(q0 + row) * E_ + h * 128 + dc * 4) = ov;
    }
}

// ---------------------------------------------------------------- out GEMM (m97 structure)
__global__ __launch_bounds__(256) void gemm_out(const f16* __restrict__ A,
                                                const f16* __restrict__ B,
                                                const float* __restrict__ bias,
                                                float* __restrict__ Cout) {
    __shared__ __align__(16) f16 As[128 * 32];
    __shared__ __align__(16) f16 Bs[128 * 32];
    const int tid  = threadIdx.x;
    const int lane = tid & 63, wave = tid >> 6;
    const int lm = lane & 15, quad = lane >> 4;
    const int wm = wave >> 1, wn = wave & 1;
    const int tn0 = blockIdx.x * 128;
    const int tm0 = blockIdx.y * 128;

    const int srow = tid >> 2, scol = (tid & 3) * 8;
    const f16* Ag0 = A + (size_t)(tm0 + srow) * E_ + scol;
    const f16* Ag1 = Ag0 + (size_t)64 * E_;
    const f16* Bg0 = B + (size_t)(tn0 + srow) * E_ + scol;
    const f16* Bg1 = Bg0 + (size_t)64 * E_;
    f16* Al0 = &As[tid * 8];
    f16* Al1 = &As[(256 + tid) * 8];
    f16* Bl0 = &Bs[tid * 8];
    f16* Bl1 = &Bs[(256 + tid) * 8];

    const f32x4 vzero = {0.f, 0.f, 0.f, 0.f};
    f32x4 acc[4][4];
#pragma unroll
    for (int i = 0; i < 4; i++)
#pragma unroll
        for (int j = 0; j < 4; j++) acc[i][j] = vzero;

    for (int k0 = 0; k0 < E_; k0 += 32) {
        __syncthreads();
        GLDS(Ag0 + k0, Al0); GLDS(Ag1 + k0, Al1);
        GLDS(Bg0 + k0, Bl0); GLDS(Bg1 + k0, Bl1);
        __syncthreads();
        f16x8 af[4], bfr[4];
#pragma unroll
        for (int i = 0; i < 4; i++)
            af[i] = *(const f16x8*)&As[(wm * 64 + i * 16 + lm) * 32 + quad * 8];
#pragma unroll
        for (int j = 0; j < 4; j++)
            bfr[j] = *(const f16x8*)&Bs[(wn * 64 + j * 16 + lm) * 32 + quad * 8];
#pragma unroll
        for (int i = 0; i < 4; i++)
#pragma unroll
            for (int j = 0; j < 4; j++)
                acc[i][j] = __builtin_amdgcn_mfma_f32_16x16x32_f16(af[i], bfr[j],
                                                                   acc[i][j], 0, 0, 0);
    }

#pragma unroll
    for (int i = 0; i < 4; i++) {
#pragma unroll
        for (int j = 0; j < 4; j++) {
            const int n = tn0 + wn * 64 + j * 16 + lm;
            const float bv = bias[n];
#pragma unroll
            for (int r = 0; r < 4; r++) {
                const int m = tm0 + wm * 64 + i * 16 + quad * 4 + r;
                Cout[(size_t)m * E_ + n] = acc[i][j][r] + bv;
            }
        }
    }
}

// ---------------------------------------------------------------- launch
extern "C" void kernel_launch(void* const* d_in, const int* in_sizes, int n_in,
                              void* d_out, int out_size, void* d_ws, size_t ws_size,
                              hipStream_t stream) {
    const float* x     = (const float*)d_in[0];
    const float* w_qkv = (const float*)d_in[1];
    const float* b_qkv = (const float*)d_in[2];
    const float* w_out = (const float*)d_in[3];
    const float* b_out = (const float*)d_in[4];
    float* out = (float*)d_out;

    char* ws = (char*)d_ws;
    f16* xb  = (f16*)ws; ws += (size_t)S_ * E_ * 2;       // 8 MB
    f16* wqb = (f16*)ws; ws += (size_t)3 * E_ * E_ * 2;   // 25 MB
    f16* wob = (f16*)ws; ws += (size_t)E_ * E_ * 2;       // 8 MB
    f16* Qm  = (f16*)ws; ws += (size_t)H_ * S_ * D_ * 2;  // 8 MB
    f16* Km  = (f16*)ws; ws += (size_t)H_ * S_ * D_ * 2;  // 8 MB
    f16* VTm = (f16*)ws; ws += (size_t)H_ * D_ * S_ * 2;  // 8 MB
    f16* Om  = (f16*)ws; ws += (size_t)S_ * E_ * 2;       // 8 MB
    float*  Opart  = (float*)ws;  ws += (size_t)512 * 64 * 128 * 4;  // 16 MB
    float2* MLpart = (float2*)ws; ws += (size_t)512 * 64 * 8;        // 0.25 MB

    cvt_f32_f16<<<4096, 256, 0, stream>>>(x, xb, S_ * E_);
    cvt_f32_f16<<<12288, 256, 0, stream>>>(w_qkv, wqb, 3 * E_ * E_);
    cvt_f32_f16<<<4096, 256, 0, stream>>>(w_out, wob, E_ * E_);
    gemm_qkv<<<dim3(48, 16), 256, 0, stream>>>(xb, wqb, b_qkv, Qm, Km, VTm);
    attn<<<768, 256, 0, stream>>>(Qm, Km, VTm, Om, Opart, MLpart);
    attn_combine<<<256, 256, 0, stream>>>(Opart, MLpart, Om);
    gemm_out<<<dim3(16, 16), 256, 0, stream>>>(Om, wob, b_out, out);
}